// Round 3
// baseline (538.132 us; speedup 1.0000x reference)
//
#include <hip/hip_runtime.h>

#define EPS_ALPHA 1e-5f

// Native clang vector type — __builtin_nontemporal_store requires this
// (HIP's float4 is a class and is rejected).
typedef float vfloat4 __attribute__((ext_vector_type(4)));

// Full DeepPoly ReLU6 relaxation for one neuron — identical guarded formulas
// to the JAX reference (masks mutually exclusive, non-selected terms exact 0,
// so nested selects are bit-equivalent). Verified absmax 0.0 in round 1.
static __device__ __forceinline__ void relax(float l, float u,
    float& cl, float& cu, float& dl, float& du, float& bl, float& bu) {
    float den_ul = (u > l)    ? (u - l)    : 1.0f;
    float den_6l = (l < 6.0f) ? (6.0f - l) : 1.0f;
    float u_safe = (u > 0.0f) ? u          : 1.0f;

    bool mA = (u > 0.0f) && (u <= 6.0f) && (l >= 0.0f);
    bool mB = (u > 0.0f) && (u <= 6.0f) && (l < 0.0f);
    bool mC = (u > 6.0f) && (l <= 0.0f);
    bool mD = (u > 6.0f) && (l > 0.0f) && (l <= 6.0f);
    bool mE = (l > 6.0f);

    float alpha_B = (u < -l) ? EPS_ALPHA : 1.0f;
    float lam_B   = u / den_ul;
    bool  us      = ((u - 6.0f) < (6.0f - l));
    float aU_C = us ? (6.0f / den_6l) : EPS_ALPHA;
    float aL_C = (u < -l) ? EPS_ALPHA : (6.0f / u_safe);
    float aU_D = us ? 1.0f : EPS_ALPHA;
    float aL_D = (6.0f - l) / den_ul;

    du = mA ? 1.0f : mB ? lam_B   : mC ? aU_C : mD ? aU_D : 0.0f;
    dl = mA ? 1.0f : mB ? alpha_B : mC ? aL_C : mD ? aL_D : 0.0f;
    bu = mB ? (-lam_B * l)
       : mC ? (6.0f * (1.0f - aU_C))
       : mD ? (6.0f * (1.0f - aU_D))
       : mE ? 6.0f : 0.0f;
    bl = mD ? (l * (1.0f - aL_D))
       : mE ? 6.0f : 0.0f;
    cu = mA ? u : mB ? u
       : mC ? (6.0f + aU_C * (u - 6.0f))
       : mD ? (6.0f + aU_D * (u - 6.0f))
       : mE ? 6.0f : 0.0f;
    cl = mA ? l
       : mB ? (alpha_B * l)
       : mC ? (aL_C * l)
       : mD ? l
       : mE ? 6.0f : 0.0f;
}

// Single fused kernel: writes every output element exactly once, float4 chunks.
// Layout: [0,N) cl | [N,2N) cu | [2N, 2N+M*M) A_l | [2N+M*M, 2N+2M*M) A_u.
// A_* zero except diag[i], last row (bias), corner [M-1,M-1]=1.
// Fast path (>99.8% of chunks): pure zero float4 nontemporal store.
// N is a template arg so idx/M compiles to a magic-multiply (M=8193 constant).
template<int N>
__global__ __launch_bounds__(256) void relu6_fill_all(
    const float* __restrict__ lower, const float* __restrict__ upper,
    float* __restrict__ out) {
    constexpr int       M      = N + 1;
    constexpr long long MM     = (long long)M * M;
    constexpr long long N2     = 2LL * N;
    constexpr long long TOTAL  = N2 + 2 * MM;       // 134,266,882
    constexpr long long NCHUNK = (TOTAL + 3) >> 2;  // last chunk is partial (2 elems)

    long long t      = (long long)blockIdx.x * blockDim.x + threadIdx.x;
    long long stride = (long long)gridDim.x * blockDim.x;

    for (long long ch = t; ch < NCHUNK; ch += stride) {
        long long base = ch << 2;

        // ---- fast path: 4 interior zeros of A_l/A_u ----
        if (base >= N2 && base + 3 < TOTAL) {
            long long a = base - N2;
            if (a >= MM) a -= MM;
            if (a + 3 < MM) {                        // doesn't straddle Al->Au
                int      idx = (int)a;               // < 2^31
                unsigned r   = (unsigned)idx / (unsigned)M;   // magic mul
                int      c   = idx - (int)r * M;
                bool rowEnd  = (c + 3 >= M);                      // straddles rows
                bool lastRow = (r == (unsigned)N);                // bias row
                bool hasDiag = ((unsigned)c <= r) && (r <= (unsigned)(c + 3));
                if (!rowEnd && !lastRow && !hasDiag) {
                    vfloat4 z = (vfloat4){0.f, 0.f, 0.f, 0.f};
                    __builtin_nontemporal_store(z, reinterpret_cast<vfloat4*>(out + base));
                    continue;
                }
            }
        }

        // ---- slow path: per-element (cl/cu region, diag, bias row, straddles, tail) ----
        float vals[4];
#pragma unroll
        for (int j = 0; j < 4; ++j) {
            long long i = base + j;
            float v = 0.0f;
            if (i < TOTAL) {
                if (i < N2) {                        // cl / cu vectors
                    int k = (int)i;
                    bool isCu = (k >= N);
                    if (isCu) k -= N;
                    float cl, cu, dl, du, bl, bu;
                    relax(lower[k], upper[k], cl, cu, dl, du, bl, bu);
                    v = isCu ? cu : cl;
                } else {
                    long long a = i - N2;
                    bool up_ = (a >= MM);
                    if (up_) a -= MM;
                    int      idx = (int)a;
                    unsigned r   = (unsigned)idx / (unsigned)M;
                    int      c   = idx - (int)r * M;
                    if (r == (unsigned)N) {          // bias row / corner
                        if (c == N) {
                            v = 1.0f;
                        } else {
                            float cl, cu, dl, du, bl, bu;
                            relax(lower[c], upper[c], cl, cu, dl, du, bl, bu);
                            v = up_ ? bu : bl;
                        }
                    } else if ((int)r == c) {        // diagonal
                        float cl, cu, dl, du, bl, bu;
                        relax(lower[c], upper[c], cl, cu, dl, du, bl, bu);
                        v = up_ ? du : dl;
                    }
                }
            }
            vals[j] = v;
        }
        if (base + 3 < TOTAL) {
            vfloat4 v4 = (vfloat4){vals[0], vals[1], vals[2], vals[3]};
            __builtin_nontemporal_store(v4, reinterpret_cast<vfloat4*>(out + base));
        } else {
            for (int j = 0; j < 4; ++j)
                if (base + j < TOTAL) out[base + j] = vals[j];
        }
    }
}

// Generic fallback (n != 8192; not expected): memset + scatter, known-correct.
__global__ void relu6_scatter_generic(const float* __restrict__ lower,
                                      const float* __restrict__ upper,
                                      float* __restrict__ out, int n) {
    int i = blockIdx.x * blockDim.x + threadIdx.x;
    if (i >= n) return;
    float cl, cu, dl, du, bl, bu;
    relax(lower[i], upper[i], cl, cu, dl, du, bl, bu);
    const long long M = (long long)n + 1;
    float* Al = out + 2LL * n;
    float* Au = Al + M * M;
    out[i] = cl;
    out[n + i] = cu;
    Al[(long long)i * M + i] = dl;
    Au[(long long)i * M + i] = du;
    Al[(long long)n * M + i] = bl;
    Au[(long long)n * M + i] = bu;
    if (i == 0) { Al[M * M - 1] = 1.0f; Au[M * M - 1] = 1.0f; }
}

extern "C" void kernel_launch(void* const* d_in, const int* in_sizes, int n_in,
                              void* d_out, int out_size, void* d_ws, size_t ws_size,
                              hipStream_t stream) {
    const float* lower = (const float*)d_in[0];
    const float* upper = (const float*)d_in[1];
    float* out = (float*)d_out;
    int n = in_sizes[0];

    if (n == 8192) {
        // 16384 blocks x 256 threads -> 4.19M threads, ~8 float4 chunks each,
        // consecutive lanes -> consecutive float4s (1 KiB/wave stores).
        relu6_fill_all<8192><<<16384, 256, 0, stream>>>(lower, upper, out);
    } else {
        (void)hipMemsetAsync(d_out, 0, (size_t)out_size * sizeof(float), stream);
        relu6_scatter_generic<<<(n + 255) / 256, 256, 0, stream>>>(lower, upper, out, n);
    }
}

// Round 4
// 521.372 us; speedup vs baseline: 1.0321x; 1.0321x over previous
//
#include <hip/hip_runtime.h>

#define EPS_ALPHA 1e-5f

typedef float vfloat4 __attribute__((ext_vector_type(4)));

// Full DeepPoly ReLU6 relaxation for one neuron — identical guarded formulas
// to the JAX reference (masks mutually exclusive, non-selected terms exact 0,
// so nested selects are bit-equivalent). absmax 0.0 verified (rounds 1 & 3).
static __device__ __forceinline__ void relax(float l, float u,
    float& cl, float& cu, float& dl, float& du, float& bl, float& bu) {
    float den_ul = (u > l)    ? (u - l)    : 1.0f;
    float den_6l = (l < 6.0f) ? (6.0f - l) : 1.0f;
    float u_safe = (u > 0.0f) ? u          : 1.0f;

    bool mA = (u > 0.0f) && (u <= 6.0f) && (l >= 0.0f);
    bool mB = (u > 0.0f) && (u <= 6.0f) && (l < 0.0f);
    bool mC = (u > 6.0f) && (l <= 0.0f);
    bool mD = (u > 6.0f) && (l > 0.0f) && (l <= 6.0f);
    bool mE = (l > 6.0f);

    float alpha_B = (u < -l) ? EPS_ALPHA : 1.0f;
    float lam_B   = u / den_ul;
    bool  us      = ((u - 6.0f) < (6.0f - l));
    float aU_C = us ? (6.0f / den_6l) : EPS_ALPHA;
    float aL_C = (u < -l) ? EPS_ALPHA : (6.0f / u_safe);
    float aU_D = us ? 1.0f : EPS_ALPHA;
    float aL_D = (6.0f - l) / den_ul;

    du = mA ? 1.0f : mB ? lam_B   : mC ? aU_C : mD ? aU_D : 0.0f;
    dl = mA ? 1.0f : mB ? alpha_B : mC ? aL_C : mD ? aL_D : 0.0f;
    bu = mB ? (-lam_B * l)
       : mC ? (6.0f * (1.0f - aU_C))
       : mD ? (6.0f * (1.0f - aU_D))
       : mE ? 6.0f : 0.0f;
    bl = mD ? (l * (1.0f - aL_D))
       : mE ? 6.0f : 0.0f;
    cu = mA ? u : mB ? u
       : mC ? (6.0f + aU_C * (u - 6.0f))
       : mD ? (6.0f + aU_D * (u - 6.0f))
       : mE ? 6.0f : 0.0f;
    cl = mA ? l
       : mB ? (alpha_B * l)
       : mC ? (aL_C * l)
       : mD ? l
       : mE ? 6.0f : 0.0f;
}

// Pass 1: dumb full-bandwidth zero fill over all complete float4 chunks.
// Regular (L2-cached) stores so the coalescer assembles full 128-B lines —
// same path as __amd_rocclr_fillBufferAligned which measures 6.27 TB/s here.
// NO nontemporal: the nt bit cost round 3 a 2.3x write-efficiency hit.
__global__ __launch_bounds__(256) void zero_fill(float* __restrict__ out,
                                                 long long nchunk) {
    long long t      = (long long)blockIdx.x * blockDim.x + threadIdx.x;
    long long stride = (long long)gridDim.x * blockDim.x;
    vfloat4 z = (vfloat4){0.f, 0.f, 0.f, 0.f};
    for (long long ch = t; ch < nchunk; ch += stride)
        *reinterpret_cast<vfloat4*>(out + (ch << 2)) = z;
}

// Pass 2: write the ~33K non-zeros (and the tail elements past the last full
// chunk, which all live in Au's bias row). ~2 MB of line traffic — noise.
__global__ void relu6_scatter(const float* __restrict__ lower,
                              const float* __restrict__ upper,
                              float* __restrict__ out, int n) {
    int i = blockIdx.x * blockDim.x + threadIdx.x;
    if (i >= n) return;
    float cl, cu, dl, du, bl, bu;
    relax(lower[i], upper[i], cl, cu, dl, du, bl, bu);
    const long long M = (long long)n + 1;
    float* Al = out + 2LL * n;
    float* Au = Al + M * M;
    out[i] = cl;
    out[n + i] = cu;
    Al[(long long)i * M + i] = dl;   // diagonal
    Au[(long long)i * M + i] = du;
    Al[(long long)n * M + i] = bl;   // bias row (coalesced)
    Au[(long long)n * M + i] = bu;
    if (i == 0) {
        Al[M * M - 1] = 1.0f;        // corners
        Au[M * M - 1] = 1.0f;
    }
}

extern "C" void kernel_launch(void* const* d_in, const int* in_sizes, int n_in,
                              void* d_out, int out_size, void* d_ws, size_t ws_size,
                              hipStream_t stream) {
    const float* lower = (const float*)d_in[0];
    const float* upper = (const float*)d_in[1];
    float* out = (float*)d_out;
    int n = in_sizes[0];  // 8192

    // Full float4 chunks; the <=3 tail elements are always inside Au's bias
    // row (row length n+1 > 3), which relu6_scatter rewrites entirely.
    long long nchunk = (long long)out_size >> 2;

    // 16384 blocks x 256 threads: 4.19M lanes, ~8 chunks each, consecutive
    // lanes -> consecutive float4s (1 KiB per wave store instruction).
    zero_fill<<<16384, 256, 0, stream>>>(out, nchunk);
    relu6_scatter<<<(n + 255) / 256, 256, 0, stream>>>(lower, upper, out, n);
}